// Round 3
// baseline (258.083 us; speedup 1.0000x reference)
//
#include <hip/hip_runtime.h>

// Problem: B=16, LX=2048, LR=1024, D=768, T=LX+LR+3=3075
// out[b,t,:] =
//   t==0                       -> CLS
//   1 <= t <= lx[b]            -> X[b, t-1, :]
//   t == lx[b]+1               -> RING
//   lx[b]+2 <= t < lx[b]+2+lr  -> Xr[b, t-lx[b]-2, :]
//   t == lx[b]+lr[b]+2         -> END
//   else                       -> 0
//
// R6: R5 structure (8 rows / 192-thread block, 2D grid, block-uniform
// branches) with ALL nontemporal hints REMOVED.
// Evidence: rocprof shows __amd_rocclr_fillBufferAligned sustaining
// 6.6 TB/s (82% peak) with plain stores on this machine, while our
// NT-hinted kernel runs ~2x slower per byte; and R4 (1 row/block) vs
// R5 (8 rows/block, 8x MLP) were within 3% -> MLP/launch overhead is
// not the limiter. Remaining structural difference vs the fast fill
// path: the `nt` cache-bypass flags. Plain loads also allow X/Xr
// (151 MB total, < 256 MB L3) to hit Infinity Cache.

constexpr int B_  = 16;
constexpr int LX_ = 2048;
constexpr int LR_ = 1024;
constexpr int D_  = 768;
constexpr int T_  = LX_ + LR_ + 3;           // 3075
constexpr int RPB = 8;                       // rows (t values) per block
constexpr int NTL = (T_ + RPB - 1) / RPB;    // 385 t-tiles (last has 3 rows)

typedef float vfloat4 __attribute__((ext_vector_type(4)));

__global__ __launch_bounds__(192)
void assemble_rows_kernel(const float* __restrict__ X,
                          const float* __restrict__ Xr,
                          const float* __restrict__ CLS,
                          const float* __restrict__ RING,
                          const float* __restrict__ END,
                          const int* __restrict__ lx,
                          const int* __restrict__ lr,
                          float* __restrict__ out)
{
    const int b   = blockIdx.y;              // uniform
    const int t0  = blockIdx.x * RPB;        // uniform
    const int lxb = lx[b];                   // uniform -> s_load
    const int lrb = lr[b];
    const int doff = threadIdx.x * 4;        // float offset within row

    const float* __restrict__ Xb   = X  + ((size_t)b * LX_) * D_ + doff;
    const float* __restrict__ Xrb  = Xr + ((size_t)b * LR_) * D_ + doff;
    float* __restrict__ outp = out + ((size_t)b * T_ + t0) * D_ + doff;

    vfloat4 v[RPB];

    #pragma unroll
    for (int i = 0; i < RPB; ++i) {
        const int t = t0 + i;
        v[i] = (vfloat4)(0.f);
        if (t >= T_) continue;               // tail tile only
        if (t == 0) {
            v[i] = *reinterpret_cast<const vfloat4*>(CLS + doff);
        } else if (t <= lxb) {
            v[i] = *reinterpret_cast<const vfloat4*>(Xb + (size_t)(t - 1) * D_);
        } else if (t == lxb + 1) {
            v[i] = *reinterpret_cast<const vfloat4*>(RING + doff);
        } else if (t < lxb + 2 + lrb) {
            v[i] = *reinterpret_cast<const vfloat4*>(Xrb + (size_t)(t - lxb - 2) * D_);
        } else if (t == lxb + lrb + 2) {
            v[i] = *reinterpret_cast<const vfloat4*>(END + doff);
        }
    }

    #pragma unroll
    for (int i = 0; i < RPB; ++i) {
        if (t0 + i < T_) {
            *reinterpret_cast<vfloat4*>(outp + (size_t)i * D_) = v[i];
        }
    }
}

extern "C" void kernel_launch(void* const* d_in, const int* in_sizes, int n_in,
                              void* d_out, int out_size, void* d_ws, size_t ws_size,
                              hipStream_t stream)
{
    const float* X    = (const float*)d_in[0];
    const float* Xr   = (const float*)d_in[1];
    const float* CLS  = (const float*)d_in[2];
    const float* RING = (const float*)d_in[3];
    const float* END  = (const float*)d_in[4];
    const int* lx = (const int*)d_in[5];
    const int* lr = (const int*)d_in[6];
    float* out = (float*)d_out;

    hipLaunchKernelGGL(assemble_rows_kernel, dim3(NTL, B_), dim3(192), 0, stream,
                       X, Xr, CLS, RING, END, lx, lr, out);
}

// Round 4
// 249.062 us; speedup vs baseline: 1.0362x; 1.0362x over previous
//
#include <hip/hip_runtime.h>

// Problem: B=16, LX=2048, LR=1024, D=768, T=LX+LR+3=3075
// out[b,t,:] =
//   t==0                       -> CLS
//   1 <= t <= lx[b]            -> X[b, t-1, :]
//   t == lx[b]+1               -> RING
//   lx[b]+2 <= t < lx[b]+2+lr  -> Xr[b, t-lx[b]-2, :]
//   t == lx[b]+lr[b]+2         -> END
//   else                       -> 0
//
// R7: NT loads + PLAIN stores (the untested quadrant).
// Evidence chain: R4(NT/NT)=242, R5(NT/NT,8row)=249, R6(plain/plain)=258;
// our kernel is <89us per dispatch (absent from top-5), headline includes
// ~180us of 604MB re-poison fills. Theory: the poison fill leaves out's
// 151MB DIRTY in L3. Plain loads (R6) evict those lines -> useless poison
// writebacks to HBM (worst). NT stores (R4/R5) bypass L3 so the poison
// writeback still happens AND stores pay full HBM cost. NT loads keep
// X/Xr from polluting L3; plain stores overwrite the dirty poison
// in-cache (poison never reaches HBM) and complete at L3 speed.
// Kernel HBM traffic drops to the compulsory ~227MB.

constexpr int B_  = 16;
constexpr int LX_ = 2048;
constexpr int LR_ = 1024;
constexpr int D_  = 768;
constexpr int T_  = LX_ + LR_ + 3;           // 3075
constexpr int RPB = 8;                       // rows (t values) per block
constexpr int NTL = (T_ + RPB - 1) / RPB;    // 385 t-tiles (last has 3 rows)

typedef float vfloat4 __attribute__((ext_vector_type(4)));

__global__ __launch_bounds__(192)
void assemble_rows_kernel(const float* __restrict__ X,
                          const float* __restrict__ Xr,
                          const float* __restrict__ CLS,
                          const float* __restrict__ RING,
                          const float* __restrict__ END,
                          const int* __restrict__ lx,
                          const int* __restrict__ lr,
                          float* __restrict__ out)
{
    const int b   = blockIdx.y;              // uniform
    const int t0  = blockIdx.x * RPB;        // uniform
    const int lxb = lx[b];                   // uniform -> s_load
    const int lrb = lr[b];
    const int doff = threadIdx.x * 4;        // float offset within row

    const float* __restrict__ Xb   = X  + ((size_t)b * LX_) * D_ + doff;
    const float* __restrict__ Xrb  = Xr + ((size_t)b * LR_) * D_ + doff;
    float* __restrict__ outp = out + ((size_t)b * T_ + t0) * D_ + doff;

    vfloat4 v[RPB];

    #pragma unroll
    for (int i = 0; i < RPB; ++i) {
        const int t = t0 + i;
        v[i] = (vfloat4)(0.f);
        if (t >= T_) continue;               // tail tile only
        if (t == 0) {
            v[i] = *reinterpret_cast<const vfloat4*>(CLS + doff);
        } else if (t <= lxb) {
            v[i] = __builtin_nontemporal_load(
                reinterpret_cast<const vfloat4*>(Xb + (size_t)(t - 1) * D_));
        } else if (t == lxb + 1) {
            v[i] = *reinterpret_cast<const vfloat4*>(RING + doff);
        } else if (t < lxb + 2 + lrb) {
            v[i] = __builtin_nontemporal_load(
                reinterpret_cast<const vfloat4*>(Xrb + (size_t)(t - lxb - 2) * D_));
        } else if (t == lxb + lrb + 2) {
            v[i] = *reinterpret_cast<const vfloat4*>(END + doff);
        }
    }

    #pragma unroll
    for (int i = 0; i < RPB; ++i) {
        if (t0 + i < T_) {
            *reinterpret_cast<vfloat4*>(outp + (size_t)i * D_) = v[i];  // plain store
        }
    }
}

extern "C" void kernel_launch(void* const* d_in, const int* in_sizes, int n_in,
                              void* d_out, int out_size, void* d_ws, size_t ws_size,
                              hipStream_t stream)
{
    const float* X    = (const float*)d_in[0];
    const float* Xr   = (const float*)d_in[1];
    const float* CLS  = (const float*)d_in[2];
    const float* RING = (const float*)d_in[3];
    const float* END  = (const float*)d_in[4];
    const int* lx = (const int*)d_in[5];
    const int* lr = (const int*)d_in[6];
    float* out = (float*)d_out;

    hipLaunchKernelGGL(assemble_rows_kernel, dim3(NTL, B_), dim3(192), 0, stream,
                       X, Xr, CLS, RING, END, lx, lr, out);
}

// Round 5
// 247.327 us; speedup vs baseline: 1.0435x; 1.0070x over previous
//
#include <hip/hip_runtime.h>

// Problem: B=16, LX=2048, LR=1024, D=768, T=LX+LR+3=3075
// out[b,t,:] =
//   t==0                       -> CLS
//   1 <= t <= lx[b]            -> X[b, t-1, :]
//   t == lx[b]+1               -> RING
//   lx[b]+2 <= t < lx[b]+2+lr  -> Xr[b, t-lx[b]-2, :]
//   t == lx[b]+lr[b]+2         -> END
//   else                       -> 0
//
// R8: persistent grid-stride kernel over the FLAT float4 index space of out
// (mimics the 6.3-6.7 TB/s fill / float4-copy structure exactly).
//  - 2048 blocks x 256 threads, grid-stride: globally-LINEAR store walk
//    (the whole grid covers one contiguous 8 MB window per step), long-lived
//    blocks (no per-block s_load preamble x6160).
//  - 2-deep manual unroll: 2 independent NT loads in flight per lane.
//  - Wave-uniform routing: a wave (64 f4 = 1024 B) never crosses a row
//    boundary (row = 192 f4, 64 | 192), so the region branch is uniform.
// Evidence: R4/R5/R6/R7 (one-shot row-block kernels) all ~242-258 us
// headline regardless of block count (8x), MLP (8x), or cache hints ->
// the only untested difference vs the fast streaming kernels is this
// persistent/linear structure.

constexpr int B_  = 16;
constexpr int LX_ = 2048;
constexpr int LR_ = 1024;
constexpr int D_  = 768;
constexpr int T_  = LX_ + LR_ + 3;            // 3075
constexpr int D4  = D_ / 4;                   // 192 float4 per row
constexpr unsigned NF4 = (unsigned)B_ * T_ * D4;  // 9,446,400 float4s
constexpr int NBLK = 2048;
constexpr int NTHR = 256;

typedef float vfloat4 __attribute__((ext_vector_type(4)));

__device__ __forceinline__ vfloat4 route(unsigned i,
                                         const float* __restrict__ X,
                                         const float* __restrict__ Xr,
                                         const float* __restrict__ CLS,
                                         const float* __restrict__ RING,
                                         const float* __restrict__ END,
                                         const int* __restrict__ lx,
                                         const int* __restrict__ lr)
{
    const unsigned row = i / (unsigned)D4;        // magic-mul
    const int doff = (int)(i - row * (unsigned)D4) * 4;
    const unsigned b = row / (unsigned)T_;        // magic-mul
    const int t = (int)(row - b * (unsigned)T_);
    const int lxb = lx[b];                        // wave-uniform addr -> 1 req
    const int lrb = lr[b];

    vfloat4 v = (vfloat4)(0.f);
    if (t == 0) {
        v = *reinterpret_cast<const vfloat4*>(CLS + doff);
    } else if (t <= lxb) {
        v = __builtin_nontemporal_load(reinterpret_cast<const vfloat4*>(
                X + ((size_t)(b * LX_ + (t - 1)) * D_ + doff)));
    } else if (t == lxb + 1) {
        v = *reinterpret_cast<const vfloat4*>(RING + doff);
    } else if (t < lxb + 2 + lrb) {
        v = __builtin_nontemporal_load(reinterpret_cast<const vfloat4*>(
                Xr + ((size_t)(b * LR_ + (t - lxb - 2)) * D_ + doff)));
    } else if (t == lxb + lrb + 2) {
        v = *reinterpret_cast<const vfloat4*>(END + doff);
    }
    return v;
}

__global__ __launch_bounds__(NTHR)
void assemble_flat_kernel(const float* __restrict__ X,
                          const float* __restrict__ Xr,
                          const float* __restrict__ CLS,
                          const float* __restrict__ RING,
                          const float* __restrict__ END,
                          const int* __restrict__ lx,
                          const int* __restrict__ lr,
                          float* __restrict__ out)
{
    const unsigned stride = NBLK * NTHR;          // 524288
    unsigned i = blockIdx.x * NTHR + threadIdx.x;

    // main: 2 f4s per trip, one grid-stride apart -> 2 loads in flight
    while (i + stride < NF4) {
        vfloat4 v0 = route(i,          X, Xr, CLS, RING, END, lx, lr);
        vfloat4 v1 = route(i + stride, X, Xr, CLS, RING, END, lx, lr);
        __builtin_nontemporal_store(v0,
            reinterpret_cast<vfloat4*>(out + (size_t)i * 4));
        __builtin_nontemporal_store(v1,
            reinterpret_cast<vfloat4*>(out + (size_t)(i + stride) * 4));
        i += 2 * stride;
    }
    // tail
    while (i < NF4) {
        vfloat4 v = route(i, X, Xr, CLS, RING, END, lx, lr);
        __builtin_nontemporal_store(v,
            reinterpret_cast<vfloat4*>(out + (size_t)i * 4));
        i += stride;
    }
}

extern "C" void kernel_launch(void* const* d_in, const int* in_sizes, int n_in,
                              void* d_out, int out_size, void* d_ws, size_t ws_size,
                              hipStream_t stream)
{
    const float* X    = (const float*)d_in[0];
    const float* Xr   = (const float*)d_in[1];
    const float* CLS  = (const float*)d_in[2];
    const float* RING = (const float*)d_in[3];
    const float* END  = (const float*)d_in[4];
    const int* lx = (const int*)d_in[5];
    const int* lr = (const int*)d_in[6];
    float* out = (float*)d_out;

    hipLaunchKernelGGL(assemble_flat_kernel, dim3(NBLK), dim3(NTHR), 0, stream,
                       X, Xr, CLS, RING, END, lx, lr, out);
}

// Round 8
// 242.867 us; speedup vs baseline: 1.0627x; 1.0184x over previous
//
#include <hip/hip_runtime.h>

// Problem constants (from reference):
//   B=16, LX=2048, LR=1024, D=768, T = LX+LR+3 = 3075
// out[b,t,:] =
//   t==0                       -> CLS
//   1 <= t <= lx[b]            -> X[b, t-1, :]
//   t == lx[b]+1               -> RING
//   lx[b]+2 <= t < lx[b]+2+lr  -> Xr[b, t-lx[b]-2, :]
//   t == lx[b]+lr[b]+2         -> END
//   else                       -> 0
//
// R10: the measured-best configuration (R4: 1 row per 192-thread block,
// NT loads on X/Xr, NT stores on out, block-uniform branches) re-expressed
// with a 2D grid (t, b) instead of a flat 49200-block grid.
//  - R4's exact source failed to bench 3x this session (infra-correlated);
//    every other kernel benched. This variant keeps R4's semantics
//    (finest-grain TLP, NT hints) while changing only dispatch geometry
//    and dropping the per-block integer division.
// Session A/B ledger: R5(8row,NT/NT)=249.1, R6(plain/plain)=258.1,
// R7(NT/plain)=249.1, R8(persistent flat)=247.3, R4(prev session)=242.1.
// Kernel dispatch is <88 us in every rocprof pass; headline is dominated
// by ~178 us of harness 604 MB re-poison fills per iteration.

constexpr int B_  = 16;
constexpr int LX_ = 2048;
constexpr int LR_ = 1024;
constexpr int D_  = 768;
constexpr int T_  = LX_ + LR_ + 3;      // 3075

typedef float vfloat4 __attribute__((ext_vector_type(4)));

__global__ __launch_bounds__(192)
void assemble_row_kernel(const float* __restrict__ X,
                         const float* __restrict__ Xr,
                         const float* __restrict__ CLS,
                         const float* __restrict__ RING,
                         const float* __restrict__ END,
                         const int* __restrict__ lx,
                         const int* __restrict__ lr,
                         float* __restrict__ out)
{
    const int t = blockIdx.x;                 // uniform
    const int b = blockIdx.y;                 // uniform

    const int lxb = lx[b];                    // uniform -> s_load
    const int lrb = lr[b];
    const int doff = threadIdx.x * 4;         // float offset within row

    vfloat4 val = (vfloat4)(0.f);

    if (t == 0) {
        val = *reinterpret_cast<const vfloat4*>(CLS + doff);
    } else if (t <= lxb) {
        const float* src = X + ((size_t)(b * LX_ + (t - 1)) * D_ + doff);
        val = __builtin_nontemporal_load(reinterpret_cast<const vfloat4*>(src));
    } else if (t == lxb + 1) {
        val = *reinterpret_cast<const vfloat4*>(RING + doff);
    } else if (t < lxb + 2 + lrb) {
        const float* src = Xr + ((size_t)(b * LR_ + (t - lxb - 2)) * D_ + doff);
        val = __builtin_nontemporal_load(reinterpret_cast<const vfloat4*>(src));
    } else if (t == lxb + lrb + 2) {
        val = *reinterpret_cast<const vfloat4*>(END + doff);
    }

    __builtin_nontemporal_store(val,
        reinterpret_cast<vfloat4*>(out + ((size_t)b * T_ + t) * D_ + doff));
}

extern "C" void kernel_launch(void* const* d_in, const int* in_sizes, int n_in,
                              void* d_out, int out_size, void* d_ws, size_t ws_size,
                              hipStream_t stream)
{
    const float* X    = (const float*)d_in[0];
    const float* Xr   = (const float*)d_in[1];
    const float* CLS  = (const float*)d_in[2];
    const float* RING = (const float*)d_in[3];
    const float* END  = (const float*)d_in[4];
    const int* lx = (const int*)d_in[5];
    const int* lr = (const int*)d_in[6];
    float* out = (float*)d_out;

    hipLaunchKernelGGL(assemble_row_kernel, dim3(T_, B_), dim3(192), 0, stream,
                       X, Xr, CLS, RING, END, lx, lr, out);
}